// Round 4
// baseline (1824.582 us; speedup 1.0000x reference)
//
#include <hip/hip_runtime.h>
#include <hip/hip_bf16.h>

#define NEXP   8
#define MTOK   4096
#define KDIM   2048
#define NINTER 5632
#define NPAIR  8192   // MTOK * TOPK

#define AS3 __attribute__((address_space(3)))
#define AS1 __attribute__((address_space(1)))

typedef __attribute__((ext_vector_type(4))) float f32x4;
typedef __attribute__((ext_vector_type(8))) short s16x8;

#define MEMF   asm volatile("" ::: "memory")
#define BARX   do { MEMF; __builtin_amdgcn_s_barrier(); MEMF; } while (0)
#define SCHEDB __builtin_amdgcn_sched_barrier(0)
#define WAITV6 asm volatile("s_waitcnt vmcnt(6)" ::: "memory")
#define WAITV0 asm volatile("s_waitcnt vmcnt(0)" ::: "memory")
#define LG8    asm volatile("s_waitcnt lgkmcnt(8)" ::: "memory")
#define LG0    asm volatile("s_waitcnt lgkmcnt(0)" ::: "memory")
#define PRIO1  __builtin_amdgcn_s_setprio(1)
#define PRIO0  __builtin_amdgcn_s_setprio(0)

__device__ __forceinline__ short f2bf(float f) {
  union { float f; unsigned u; } v; v.f = f;
  unsigned r = v.u + 0x7FFFu + ((v.u >> 16) & 1u);
  return (short)(r >> 16);
}

__device__ __forceinline__ s16x8 pack8(float4 a, float4 b) {
  s16x8 v;
  v[0] = f2bf(a.x); v[1] = f2bf(a.y); v[2] = f2bf(a.z); v[3] = f2bf(a.w);
  v[4] = f2bf(b.x); v[5] = f2bf(b.y); v[6] = f2bf(b.z); v[7] = f2bf(b.w);
  return v;
}

// ---------------- fp32 -> bf16 one-shot conversion ----------------
__global__ __launch_bounds__(256) void cvt_k(const float* __restrict__ src,
                                             unsigned short* __restrict__ dst, size_t n8) {
  size_t i = (size_t)blockIdx.x * blockDim.x + threadIdx.x;
  size_t stride = (size_t)gridDim.x * blockDim.x;
  for (; i < n8; i += stride) {
    const float4* p = (const float4*)(src + i * 8);
    float4 f0 = p[0], f1 = p[1];
    *(s16x8*)(dst + i * 8) = pack8(f0, f1);
  }
}

// ---------------- routing: deterministic counting sort ----------------
__global__ __launch_bounds__(512) void route_k(const int* __restrict__ ids,
                                               int* __restrict__ off,
                                               int* __restrict__ list) {
  __shared__ int sids[NPAIR];
  __shared__ int scnt[64][8];
  __shared__ int sstart[64][8];
  __shared__ int s_is64;
  int tid = threadIdx.x;
  if (tid == 0) s_is64 = 1;
  __syncthreads();
  for (int i = tid; i < NPAIR / 2; i += 512)
    if (ids[2 * i + 1] != 0) s_is64 = 0;
  __syncthreads();
  int is64 = s_is64;
  for (int i = tid; i < NPAIR; i += 512) {
    int e = is64 ? ids[2 * i] : ids[i];
    if (e < 0) e = 0; if (e > 7) e = 7;
    sids[i] = e;
  }
  if (tid < 64)
    for (int e = 0; e < 8; ++e) scnt[tid][e] = 0;
  __syncthreads();
  if (tid < 64) {
    int b0 = tid * 128;
    for (int i = 0; i < 128; ++i) ++scnt[tid][sids[b0 + i]];
  }
  __syncthreads();
  if (tid == 0) {
    int tot = 0;
    for (int e = 0; e < 8; ++e) {
      off[e] = tot;
      for (int c = 0; c < 64; ++c) { sstart[c][e] = tot; tot += scnt[c][e]; }
    }
    off[8] = tot;
  }
  __syncthreads();
  if (tid < 64) {
    int b0 = tid * 128;
    for (int i = 0; i < 128; ++i) {
      int p = b0 + i;
      int e = sids[p];
      list[sstart[tid][e]++] = p;
    }
  }
}

// ============ GEMM1 8-phase: BM=256 (tokens), 128 gate + 128 up cols, BK=64, 512 thr ============
// Waves 4M x 2N: wave owns 64 rows x 64 inter-cols (gate acc + up acc).
// LDS dbuf (32768 shorts): A [0,16384) | G [16384,24576) | U [24576,32768).
// Stage units (8KB, 1 gload/thread): A0-A3 (64 rows each), G0,G1, U0,U1.
// w2 fp32->bf16 conversion appended at block END (overlaps other blocks' compute).
__global__ __launch_bounds__(512, 2) void gemm1_k8(const float* __restrict__ w2f,
                                                   unsigned short* __restrict__ w2b,
                                                   const unsigned short* __restrict__ a1b,
                                                   const unsigned short* __restrict__ w1b,
                                                   const int* __restrict__ off,
                                                   const int* __restrict__ list,
                                                   unsigned short* __restrict__ act) {
  extern __shared__ __align__(16) char smem[];
  short* sm = (short*)smem;
  __shared__ int srow[256];

  int e = blockIdx.z, mt = blockIdx.y, nt = blockIdx.x;
  int base = off[e];
  int cnt  = off[e + 1] - base;
  int tid = threadIdx.x;
  bool work = (mt * 256 < cnt);

  if (work) {
    for (int i = tid; i < 256; i += 512) {
      int r = mt * 256 + i;
      srow[i] = (r < cnt) ? (list[base + r] >> 1) : (list[base + cnt - 1] >> 1);
    }
    __syncthreads();

    int lane = tid & 63, w = tid >> 6;
    int wm = w >> 1, wn = w & 1;
    int lrow = lane & 15, lhi = lane >> 4;
    int l8 = lane >> 3, c8 = lane & 7;

    f32x4 accg[4][4], accu[4][4];
#pragma unroll
    for (int i = 0; i < 4; ++i)
#pragma unroll
      for (int j = 0; j < 4; ++j) { accg[i][j] = (f32x4)(0.f); accu[i][j] = (f32x4)(0.f); }

    const unsigned short* w1be = w1b + (size_t)e * (2 * NINTER) * KDIM;
    int swz = (c8 ^ l8) * 8;
    const unsigned short* sA[4]; int aD[4];
    const unsigned short* sG[2]; int gD[2];
    const unsigned short* sU[2]; int uD[2];
#pragma unroll
    for (int u = 0; u < 4; ++u) {
      int r = u * 64 + w * 8 + l8;
      sA[u] = a1b + (size_t)srow[r] * KDIM + swz;
      aD[u] = (u * 64 + w * 8) * 64;
    }
#pragma unroll
    for (int u = 0; u < 2; ++u) {
      int r = u * 64 + w * 8 + l8;
      sG[u] = w1be + (size_t)(nt * 128 + r) * KDIM + swz;
      sU[u] = w1be + (size_t)(NINTER + nt * 128 + r) * KDIM + swz;
      gD[u] = 16384 + (u * 64 + w * 8) * 64;
      uD[u] = 24576 + (u * 64 + w * 8) * 64;
    }

    auto STA = [&](int u, int d, int t) {
      __builtin_amdgcn_global_load_lds((const AS1 void*)(sA[u] + t * 64), (AS3 void*)(sm + d * 32768 + aD[u]), 16, 0, 0);
    };
    auto STG = [&](int u, int d, int t) {
      __builtin_amdgcn_global_load_lds((const AS1 void*)(sG[u] + t * 64), (AS3 void*)(sm + d * 32768 + gD[u]), 16, 0, 0);
    };
    auto STU = [&](int u, int d, int t) {
      __builtin_amdgcn_global_load_lds((const AS1 void*)(sU[u] + t * 64), (AS3 void*)(sm + d * 32768 + uD[u]), 16, 0, 0);
    };
    auto LDA = [&](int d, int i0, s16x8 (&af)[2][2]) {
#pragma unroll
      for (int ii = 0; ii < 2; ++ii)
#pragma unroll
        for (int kk = 0; kk < 2; ++kk) {
          int r = wm * 64 + i0 * 32 + ii * 16 + lrow, ch = kk * 4 + lhi;
          af[ii][kk] = *(const s16x8*)&sm[d * 32768 + r * 64 + ((ch ^ (r & 7)) * 8)];
        }
    };
    auto LDG = [&](int d, s16x8 (&bf)[4][2]) {
#pragma unroll
      for (int jj = 0; jj < 4; ++jj)
#pragma unroll
        for (int kk = 0; kk < 2; ++kk) {
          int r = wn * 64 + jj * 16 + lrow, ch = kk * 4 + lhi;
          bf[jj][kk] = *(const s16x8*)&sm[d * 32768 + 16384 + r * 64 + ((ch ^ (r & 7)) * 8)];
        }
    };
    auto LDU = [&](int d, s16x8 (&bf)[4][2]) {
#pragma unroll
      for (int jj = 0; jj < 4; ++jj)
#pragma unroll
        for (int kk = 0; kk < 2; ++kk) {
          int r = wn * 64 + jj * 16 + lrow, ch = kk * 4 + lhi;
          bf[jj][kk] = *(const s16x8*)&sm[d * 32768 + 24576 + r * 64 + ((ch ^ (r & 7)) * 8)];
        }
    };
    auto QG = [&](int i0, s16x8 (&af)[2][2], s16x8 (&bf)[4][2]) {
#pragma unroll
      for (int ii = 0; ii < 2; ++ii)
#pragma unroll
        for (int jj = 0; jj < 4; ++jj)
#pragma unroll
          for (int kk = 0; kk < 2; ++kk)
            accg[i0 * 2 + ii][jj] = __builtin_amdgcn_mfma_f32_16x16x32_bf16(af[ii][kk], bf[jj][kk], accg[i0 * 2 + ii][jj], 0, 0, 0);
    };
    auto QU = [&](int i0, s16x8 (&af)[2][2], s16x8 (&bf)[4][2]) {
#pragma unroll
      for (int ii = 0; ii < 2; ++ii)
#pragma unroll
        for (int jj = 0; jj < 4; ++jj)
#pragma unroll
          for (int kk = 0; kk < 2; ++kk)
            accu[i0 * 2 + ii][jj] = __builtin_amdgcn_mfma_f32_16x16x32_bf16(af[ii][kk], bf[jj][kk], accu[i0 * 2 + ii][jj], 0, 0, 0);
    };

    // prologue: tile0 all 8 units -> dbuf0; tile1: G,U,A0,A1 -> dbuf1 (A2,A3 at iter0.P1)
    STA(0, 0, 0); STA(1, 0, 0); STA(2, 0, 0); STA(3, 0, 0);
    STG(0, 0, 0); STG(1, 0, 0); STU(0, 0, 0); STU(1, 0, 0);
    STG(0, 1, 1); STG(1, 1, 1); STU(0, 1, 1); STU(1, 1, 1);
    STA(0, 1, 1); STA(1, 1, 1);
    WAITV6; SCHEDB;
    BARX;

    const int NI = (KDIM / 64) / 2;   // 16
#pragma unroll 1
    for (int I = 0; I < NI; ++I) {
      int t = 2 * I;
      bool pf = (I + 1 < NI);
      s16x8 af[2][2], bg[4][2], bu[4][2];
      // P1
      LDA(0, 0, af); LDG(0, bg);
      STA(2, 1, t + 1); STA(3, 1, t + 1);
      LG8; BARX; LG0; SCHEDB;
      PRIO1; QG(0, af, bg); PRIO0;
      BARX;
      // P2
      LDU(0, bu);
      if (pf) { STG(0, 0, t + 2); STG(1, 0, t + 2); }
      BARX; LG0; SCHEDB;
      PRIO1; QU(0, af, bu); PRIO0;
      BARX;
      // P3
      LDA(0, 1, af);
      if (pf) { STU(0, 0, t + 2); STU(1, 0, t + 2); }
      BARX; LG0; SCHEDB;
      PRIO1; QG(1, af, bg); PRIO0;
      BARX;
      // P4
      if (pf) { STA(0, 0, t + 2); STA(1, 0, t + 2); }
      BARX;
      PRIO1; QU(1, af, bu); PRIO0;
      if (pf) { WAITV6; } else { WAITV0; }
      SCHEDB;
      BARX;
      // P5
      LDA(1, 0, af); LDG(1, bg);
      if (pf) { STA(2, 0, t + 2); STA(3, 0, t + 2); }
      LG8; BARX; LG0; SCHEDB;
      PRIO1; QG(0, af, bg); PRIO0;
      BARX;
      // P6
      LDU(1, bu);
      if (pf) { STG(0, 1, t + 3); STG(1, 1, t + 3); }
      BARX; LG0; SCHEDB;
      PRIO1; QU(0, af, bu); PRIO0;
      BARX;
      // P7
      LDA(1, 1, af);
      if (pf) { STU(0, 1, t + 3); STU(1, 1, t + 3); }
      BARX; LG0; SCHEDB;
      PRIO1; QG(1, af, bg); PRIO0;
      BARX;
      // P8
      if (pf) { STA(0, 1, t + 3); STA(1, 1, t + 3); }
      BARX;
      PRIO1; QU(1, af, bu); PRIO0;
      if (pf) { WAITV6; SCHEDB; }
      BARX;
    }

    // epilogue: SwiGLU -> act bf16
#pragma unroll
    for (int i = 0; i < 4; ++i) {
#pragma unroll
      for (int q = 0; q < 4; ++q) {
        int grow = mt * 256 + wm * 64 + i * 16 + lhi * 4 + q;
        if (grow < cnt) {
          size_t rowoff = (size_t)(base + grow) * NINTER;
#pragma unroll
          for (int j = 0; j < 4; ++j) {
            float g = accg[i][j][q], u = accu[i][j][q];
            float a = (g / (1.f + __expf(-g))) * u;
            int col = nt * 128 + wn * 64 + j * 16 + lrow;
            act[rowoff + col] = (unsigned short)f2bf(a);
          }
        }
      }
    }
  }

  // ---- w2 cvt tail: 11264 blocks x 1024 float8-groups = 11,534,336 exactly ----
  {
    size_t bid = blockIdx.x + 44u * (blockIdx.y + 32u * blockIdx.z);
    size_t g = bid * 1024 + tid;
    const float4* s = (const float4*)(w2f + g * 8);
    float4 f0 = s[0], f1 = s[1];
    *(s16x8*)(w2b + g * 8) = pack8(f0, f1);
    g += 512;
    s = (const float4*)(w2f + g * 8);
    f0 = s[0]; f1 = s[1];
    *(s16x8*)(w2b + g * 8) = pack8(f0, f1);
  }
}

// ============ GEMM2 8-phase: BM=256, BN=256, BK=64 over INTER, 512 thr ============
// Waves 2M x 4N: wave owns 128 rows x 64 cols.
// LDS dbuf (32768 shorts): A [0,16384) | B [16384,32768). Units A0-A3, B0-B3 (64 rows each).
__global__ __launch_bounds__(512, 2) void gemm2_k8(const unsigned short* __restrict__ act,
                                                   const unsigned short* __restrict__ w2b,
                                                   const int* __restrict__ off,
                                                   const int* __restrict__ list,
                                                   const float* __restrict__ tw,
                                                   float* __restrict__ out) {
  extern __shared__ __align__(16) char smem[];
  short* sm = (short*)smem;

  int e = blockIdx.z, mt = blockIdx.y, nt = blockIdx.x;
  int base = off[e];
  int cnt  = off[e + 1] - base;
  if (mt * 256 >= cnt) return;

  int tid = threadIdx.x;
  int lane = tid & 63, w = tid >> 6;
  int wm = w >> 2, wn = w & 3;
  int lrow = lane & 15, lhi = lane >> 4;
  int l8 = lane >> 3, c8 = lane & 7;

  f32x4 acc[8][4];
#pragma unroll
  for (int i = 0; i < 8; ++i)
#pragma unroll
    for (int j = 0; j < 4; ++j) acc[i][j] = (f32x4)(0.f);

  const unsigned short* w2be = w2b + (size_t)e * KDIM * NINTER;
  int swz = (c8 ^ l8) * 8;
  const unsigned short* sA[4]; const unsigned short* sB[4];
  int aD[4], bD[4];
#pragma unroll
  for (int u = 0; u < 4; ++u) {
    int r = u * 64 + w * 8 + l8;
    int g = mt * 256 + r; if (g >= cnt) g = cnt - 1;
    sA[u] = act + (size_t)(base + g) * NINTER + swz;
    sB[u] = w2be + (size_t)(nt * 256 + r) * NINTER + swz;
    aD[u] = (u * 64 + w * 8) * 64;
    bD[u] = 16384 + (u * 64 + w * 8) * 64;
  }

  auto STA = [&](int u, int d, int t) {
    __builtin_amdgcn_global_load_lds((const AS1 void*)(sA[u] + t * 64), (AS3 void*)(sm + d * 32768 + aD[u]), 16, 0, 0);
  };
  auto STB = [&](int u, int d, int t) {
    __builtin_amdgcn_global_load_lds((const AS1 void*)(sB[u] + t * 64), (AS3 void*)(sm + d * 32768 + bD[u]), 16, 0, 0);
  };
  auto LDA = [&](int d, int i0, s16x8 (&af)[4][2]) {
#pragma unroll
    for (int ii = 0; ii < 4; ++ii)
#pragma unroll
      for (int kk = 0; kk < 2; ++kk) {
        int r = wm * 128 + i0 * 64 + ii * 16 + lrow, ch = kk * 4 + lhi;
        af[ii][kk] = *(const s16x8*)&sm[d * 32768 + r * 64 + ((ch ^ (r & 7)) * 8)];
      }
  };
  auto LDB = [&](int d, int j0, s16x8 (&bf)[2][2]) {
#pragma unroll
    for (int jj = 0; jj < 2; ++jj)
#pragma unroll
      for (int kk = 0; kk < 2; ++kk) {
        int r = wn * 64 + j0 * 32 + jj * 16 + lrow, ch = kk * 4 + lhi;
        bf[jj][kk] = *(const s16x8*)&sm[d * 32768 + 16384 + r * 64 + ((ch ^ (r & 7)) * 8)];
      }
  };
  auto QUAD = [&](int i0, int j0, s16x8 (&af)[4][2], s16x8 (&bf)[2][2]) {
#pragma unroll
    for (int ii = 0; ii < 4; ++ii)
#pragma unroll
      for (int jj = 0; jj < 2; ++jj)
#pragma unroll
        for (int kk = 0; kk < 2; ++kk)
          acc[i0 * 4 + ii][j0 * 2 + jj] = __builtin_amdgcn_mfma_f32_16x16x32_bf16(af[ii][kk], bf[jj][kk], acc[i0 * 4 + ii][j0 * 2 + jj], 0, 0, 0);
  };

  // prologue: tile0 all 8 units -> dbuf0; tile1: A0-A3,B0,B1 -> dbuf1 (B2,B3 at iter0.P1)
  STA(0, 0, 0); STA(1, 0, 0); STA(2, 0, 0); STA(3, 0, 0);
  STB(0, 0, 0); STB(1, 0, 0); STB(2, 0, 0); STB(3, 0, 0);
  STA(0, 1, 1); STA(1, 1, 1); STA(2, 1, 1); STA(3, 1, 1);
  STB(0, 1, 1); STB(1, 1, 1);
  WAITV6; SCHEDB;
  BARX;

  const int NI = (NINTER / 64) / 2;   // 44
#pragma unroll 1
  for (int I = 0; I < NI; ++I) {
    int t = 2 * I;
    bool pf = (I + 1 < NI);
    s16x8 af[4][2], b0[2][2], b1[2][2];
    // P1
    LDA(0, 0, af); LDB(0, 0, b0);
    STB(2, 1, t + 1); STB(3, 1, t + 1);
    LG8; BARX; LG0; SCHEDB;
    PRIO1; QUAD(0, 0, af, b0); PRIO0;
    BARX;
    // P2
    LDB(0, 1, b1);
    if (pf) { STA(0, 0, t + 2); STA(2, 0, t + 2); }
    BARX; LG0; SCHEDB;
    PRIO1; QUAD(0, 1, af, b1); PRIO0;
    BARX;
    // P3
    LDA(0, 1, af);
    if (pf) { STB(0, 0, t + 2); STB(1, 0, t + 2); }
    BARX; LG0; SCHEDB;
    PRIO1; QUAD(1, 0, af, b0); PRIO0;
    BARX;
    // P4
    if (pf) { STA(1, 0, t + 2); STA(3, 0, t + 2); }
    BARX;
    PRIO1; QUAD(1, 1, af, b1); PRIO0;
    if (pf) { WAITV6; } else { WAITV0; }
    SCHEDB;
    BARX;
    // P5
    LDA(1, 0, af); LDB(1, 0, b0);
    if (pf) { STB(2, 0, t + 2); STB(3, 0, t + 2); }
    LG8; BARX; LG0; SCHEDB;
    PRIO1; QUAD(0, 0, af, b0); PRIO0;
    BARX;
    // P6
    LDB(1, 1, b1);
    if (pf) { STA(0, 1, t + 3); STA(2, 1, t + 3); }
    BARX; LG0; SCHEDB;
    PRIO1; QUAD(0, 1, af, b1); PRIO0;
    BARX;
    // P7
    LDA(1, 1, af);
    if (pf) { STB(0, 1, t + 3); STB(1, 1, t + 3); }
    BARX; LG0; SCHEDB;
    PRIO1; QUAD(1, 0, af, b0); PRIO0;
    BARX;
    // P8
    if (pf) { STA(1, 1, t + 3); STA(3, 1, t + 3); }
    BARX;
    PRIO1; QUAD(1, 1, af, b1); PRIO0;
    if (pf) { WAITV6; SCHEDB; }
    BARX;
  }

  // epilogue: weighted atomic scatter
#pragma unroll
  for (int i = 0; i < 8; ++i) {
#pragma unroll
    for (int q = 0; q < 4; ++q) {
      int grow = mt * 256 + wm * 128 + i * 16 + lhi * 4 + q;
      if (grow < cnt) {
        int p = list[base + grow];
        int m = p >> 1;
        float wgt = tw[p];
#pragma unroll
        for (int j = 0; j < 4; ++j) {
          int col = nt * 256 + wn * 64 + j * 16 + lrow;
          atomicAdd(&out[(size_t)m * KDIM + col], wgt * acc[i][j][q]);
        }
      }
    }
  }
}

// ============ fallback (fp32 inputs, 128^2) — used only if ws too small ============
__global__ __launch_bounds__(256, 2) void gemm1_fb(const float* __restrict__ a1,
                                                   const float* __restrict__ w1,
                                                   const int* __restrict__ off,
                                                   const int* __restrict__ list,
                                                   unsigned short* __restrict__ act) {
  int e = blockIdx.z, mt = blockIdx.y, nt = blockIdx.x;
  int base = off[e];
  int cnt  = off[e + 1] - base;
  if (mt * 128 >= cnt) return;
  __shared__ __align__(16) short lA[128 * 64];
  __shared__ __align__(16) short lBg[128 * 64];
  __shared__ __align__(16) short lBu[128 * 64];
  __shared__ int srow[128];
  int tid = threadIdx.x;
  if (tid < 128) {
    int r = mt * 128 + tid;
    srow[tid] = (r < cnt) ? (list[base + r] >> 1) : 0;
  }
  __syncthreads();
  int lane = tid & 63, wave = tid >> 6;
  int wm = wave >> 1, wn = wave & 1;
  int lrow = lane & 15, lhi = lane >> 4;
  f32x4 accg[4][4], accu[4][4];
#pragma unroll
  for (int i = 0; i < 4; ++i)
#pragma unroll
    for (int j = 0; j < 4; ++j) { accg[i][j] = (f32x4)(0.f); accu[i][j] = (f32x4)(0.f); }
  const float* w1e = w1 + (size_t)e * (2 * NINTER) * KDIM;
  int n0 = nt * 128;
  for (int k0 = 0; k0 < KDIM; k0 += 64) {
#pragma unroll
    for (int c4 = 0; c4 < 4; ++c4) {
      int cid = c4 * 256 + tid;
      int row = cid >> 3, k8 = cid & 7;
      const float* s = a1 + (size_t)srow[row] * KDIM + k0 + k8 * 8;
      float4 f0 = *(const float4*)s;
      float4 f1 = *(const float4*)(s + 4);
      *(s16x8*)&lA[row * 64 + ((k8 ^ (row & 7)) * 8)] = pack8(f0, f1);
    }
#pragma unroll
    for (int c4 = 0; c4 < 4; ++c4) {
      int cid = c4 * 256 + tid;
      int row = cid >> 3, k8 = cid & 7;
      const float* sg = w1e + (size_t)(n0 + row) * KDIM + k0 + k8 * 8;
      const float* su = w1e + (size_t)(NINTER + n0 + row) * KDIM + k0 + k8 * 8;
      float4 g0 = *(const float4*)sg;
      float4 g1 = *(const float4*)(sg + 4);
      float4 u0 = *(const float4*)su;
      float4 u1 = *(const float4*)(su + 4);
      int o = row * 64 + ((k8 ^ (row & 7)) * 8);
      *(s16x8*)&lBg[o] = pack8(g0, g1);
      *(s16x8*)&lBu[o] = pack8(u0, u1);
    }
    __syncthreads();
#pragma unroll
    for (int kk = 0; kk < 2; ++kk) {
      s16x8 af[4], bg[4], bu[4];
      int chunk = kk * 4 + lhi;
#pragma unroll
      for (int i = 0; i < 4; ++i) {
        int r = wm * 64 + i * 16 + lrow;
        af[i] = *(const s16x8*)&lA[r * 64 + ((chunk ^ (r & 7)) * 8)];
      }
#pragma unroll
      for (int j = 0; j < 4; ++j) {
        int r = wn * 64 + j * 16 + lrow;
        int o = r * 64 + ((chunk ^ (r & 7)) * 8);
        bg[j] = *(const s16x8*)&lBg[o];
        bu[j] = *(const s16x8*)&lBu[o];
      }
#pragma unroll
      for (int i = 0; i < 4; ++i)
#pragma unroll
        for (int j = 0; j < 4; ++j) {
          accg[i][j] = __builtin_amdgcn_mfma_f32_16x16x32_bf16(af[i], bg[j], accg[i][j], 0, 0, 0);
          accu[i][j] = __builtin_amdgcn_mfma_f32_16x16x32_bf16(af[i], bu[j], accu[i][j], 0, 0, 0);
        }
    }
    __syncthreads();
  }
#pragma unroll
  for (int i = 0; i < 4; ++i) {
#pragma unroll
    for (int q = 0; q < 4; ++q) {
      int r = wm * 64 + i * 16 + lhi * 4 + q;
      int grow = mt * 128 + r;
      if (grow < cnt) {
        size_t rowoff = (size_t)(base + grow) * NINTER;
#pragma unroll
        for (int j = 0; j < 4; ++j) {
          float g = accg[i][j][q], u = accu[i][j][q];
          float a = (g / (1.f + __expf(-g))) * u;
          int col = n0 + wn * 64 + j * 16 + lrow;
          act[rowoff + col] = (unsigned short)f2bf(a);
        }
      }
    }
  }
}

__global__ __launch_bounds__(256, 2) void gemm2_fb(const unsigned short* __restrict__ act,
                                                   const float* __restrict__ w2,
                                                   const int* __restrict__ off,
                                                   const int* __restrict__ list,
                                                   const float* __restrict__ tw,
                                                   float* __restrict__ out) {
  int e = blockIdx.z, mt = blockIdx.y, nt = blockIdx.x;
  int base = off[e];
  int cnt  = off[e + 1] - base;
  if (mt * 128 >= cnt) return;
  __shared__ __align__(16) short lA[128 * 64];
  __shared__ __align__(16) short lB[128 * 64];
  int tid = threadIdx.x;
  int lane = tid & 63, wave = tid >> 6;
  int wm = wave >> 1, wn = wave & 1;
  int lrow = lane & 15, lhi = lane >> 4;
  f32x4 acc[4][4];
#pragma unroll
  for (int i = 0; i < 4; ++i)
#pragma unroll
    for (int j = 0; j < 4; ++j) acc[i][j] = (f32x4)(0.f);
  const float* w2e = w2 + (size_t)e * KDIM * NINTER;
  for (int k0 = 0; k0 < NINTER; k0 += 64) {
#pragma unroll
    for (int c4 = 0; c4 < 4; ++c4) {
      int cid = c4 * 256 + tid;
      int row = cid >> 3, k8 = cid & 7;
      int grow = mt * 128 + row;
      if (grow >= cnt) grow = cnt - 1;
      s16x8 v = *(const s16x8*)(act + (size_t)(base + grow) * NINTER + k0 + k8 * 8);
      *(s16x8*)&lA[row * 64 + ((k8 ^ (row & 7)) * 8)] = v;
    }
#pragma unroll
    for (int c4 = 0; c4 < 4; ++c4) {
      int cid = c4 * 256 + tid;
      int row = cid >> 3, k8 = cid & 7;
      const float* s = w2e + (size_t)(nt * 128 + row) * NINTER + k0 + k8 * 8;
      float4 f0 = *(const float4*)s;
      float4 f1 = *(const float4*)(s + 4);
      *(s16x8*)&lB[row * 64 + ((k8 ^ (row & 7)) * 8)] = pack8(f0, f1);
    }
    __syncthreads();
#pragma unroll
    for (int kk = 0; kk < 2; ++kk) {
      s16x8 af[4], bf[4];
      int chunk = kk * 4 + lhi;
#pragma unroll
      for (int i = 0; i < 4; ++i) {
        int r = wm * 64 + i * 16 + lrow;
        af[i] = *(const s16x8*)&lA[r * 64 + ((chunk ^ (r & 7)) * 8)];
      }
#pragma unroll
      for (int j = 0; j < 4; ++j) {
        int r = wn * 64 + j * 16 + lrow;
        bf[j] = *(const s16x8*)&lB[r * 64 + ((chunk ^ (r & 7)) * 8)];
      }
#pragma unroll
      for (int i = 0; i < 4; ++i)
#pragma unroll
        for (int j = 0; j < 4; ++j)
          acc[i][j] = __builtin_amdgcn_mfma_f32_16x16x32_bf16(af[i], bf[j], acc[i][j], 0, 0, 0);
    }
    __syncthreads();
  }
#pragma unroll
  for (int i = 0; i < 4; ++i) {
#pragma unroll
    for (int q = 0; q < 4; ++q) {
      int r = wm * 64 + i * 16 + lhi * 4 + q;
      int grow = mt * 128 + r;
      if (grow < cnt) {
        int p = list[base + grow];
        int m = p >> 1;
        float wgt = tw[p];
#pragma unroll
        for (int j = 0; j < 4; ++j) {
          int col = nt * 128 + wn * 64 + j * 16 + lrow;
          atomicAdd(&out[(size_t)m * KDIM + col], wgt * acc[i][j][q]);
        }
      }
    }
  }
}

extern "C" void kernel_launch(void* const* d_in, const int* in_sizes, int n_in,
                              void* d_out, int out_size, void* d_ws, size_t ws_size,
                              hipStream_t stream) {
  const float* a1 = (const float*)d_in[0];
  const float* w1 = (const float*)d_in[1];
  const float* w2 = (const float*)d_in[2];
  const float* tw = (const float*)d_in[3];
  const int*   ids = (const int*)d_in[4];
  float* out = (float*)d_out;

  int* off  = (int*)d_ws;
  int* list = off + 16;
  unsigned short* act = (unsigned short*)((char*)d_ws + 65536);
  size_t actB = (size_t)NPAIR * NINTER * 2;
  unsigned short* a1b = (unsigned short*)((char*)act + actB);
  size_t a1B = (size_t)MTOK * KDIM * 2;
  unsigned short* w1b = (unsigned short*)((char*)a1b + a1B);
  size_t w1B = (size_t)NEXP * 2 * NINTER * KDIM * 2;
  unsigned short* w2b = (unsigned short*)((char*)w1b + w1B);
  size_t w2B = (size_t)NEXP * KDIM * NINTER * 2;
  size_t need = 65536 + actB + a1B + w1B + w2B;

  hipMemsetAsync(d_out, 0, (size_t)MTOK * KDIM * sizeof(float), stream);
  route_k<<<1, 512, 0, stream>>>(ids, off, list);

  if (ws_size >= need) {
    hipFuncSetAttribute((const void*)gemm1_k8, hipFuncAttributeMaxDynamicSharedMemorySize, 131072);
    hipFuncSetAttribute((const void*)gemm2_k8, hipFuncAttributeMaxDynamicSharedMemorySize, 131072);
    cvt_k<<<2048, 256, 0, stream>>>(a1, a1b, (size_t)MTOK * KDIM / 8);
    cvt_k<<<2048, 256, 0, stream>>>(w1, w1b, (size_t)NEXP * 2 * NINTER * KDIM / 8);
    gemm1_k8<<<dim3(NINTER / 128, 32, NEXP), 512, 131072, stream>>>(w2, w2b, a1b, w1b, off, list, act);
    gemm2_k8<<<dim3(KDIM / 256, 32, NEXP), 512, 131072, stream>>>(act, w2b, off, list, tw, out);
  } else {
    gemm1_fb<<<dim3(NINTER / 128, 64, NEXP), 256, 0, stream>>>(a1, w1, off, list, act);
    gemm2_fb<<<dim3(KDIM / 128, 64, NEXP), 256, 0, stream>>>(act, w2, off, list, tw, out);
  }
}

// Round 5
// 1006.341 us; speedup vs baseline: 1.8131x; 1.8131x over previous
//
#include <hip/hip_runtime.h>
#include <hip/hip_bf16.h>

#define NEXP   8
#define MTOK   4096
#define KDIM   2048
#define NINTER 5632
#define NPAIR  8192   // MTOK * TOPK

#define AS3 __attribute__((address_space(3)))
#define AS1 __attribute__((address_space(1)))

typedef __attribute__((ext_vector_type(4))) float f32x4;
typedef __attribute__((ext_vector_type(8))) short s16x8;

__device__ __forceinline__ short f2bf(float f) {
  union { float f; unsigned u; } v; v.f = f;
  unsigned r = v.u + 0x7FFFu + ((v.u >> 16) & 1u);
  return (short)(r >> 16);
}

__device__ __forceinline__ s16x8 pack8(float4 a, float4 b) {
  s16x8 v;
  v[0] = f2bf(a.x); v[1] = f2bf(a.y); v[2] = f2bf(a.z); v[3] = f2bf(a.w);
  v[4] = f2bf(b.x); v[5] = f2bf(b.y); v[6] = f2bf(b.z); v[7] = f2bf(b.w);
  return v;
}

// ============ fused: routing (block 0) + a1/w1 fp32->bf16 cvt (all blocks) ============
#define N8_A1  ((size_t)MTOK * KDIM / 8)                 // 1,048,576
#define N8_W1  ((size_t)NEXP * 2 * NINTER * KDIM / 8)    // 23,068,672
__global__ __launch_bounds__(256) void routecvt_k(const int* __restrict__ ids,
                                                  int* __restrict__ off,
                                                  int* __restrict__ list,
                                                  const float* __restrict__ a1,
                                                  unsigned short* __restrict__ a1b,
                                                  const float* __restrict__ w1,
                                                  unsigned short* __restrict__ w1b) {
  int tid = threadIdx.x;
  if (blockIdx.x == 0) {
    __shared__ int sids[NPAIR];
    __shared__ int scnt[64][8];
    __shared__ int sstart[64][8];
    __shared__ int s_is64;
    if (tid == 0) s_is64 = 1;
    __syncthreads();
    for (int i = tid; i < NPAIR / 2; i += 256)
      if (ids[2 * i + 1] != 0) s_is64 = 0;   // benign race, only writes 0
    __syncthreads();
    int is64 = s_is64;
    for (int i = tid; i < NPAIR; i += 256) {
      int e = is64 ? ids[2 * i] : ids[i];
      if (e < 0) e = 0; if (e > 7) e = 7;
      sids[i] = e;
    }
    if (tid < 64)
      for (int e = 0; e < 8; ++e) scnt[tid][e] = 0;
    __syncthreads();
    if (tid < 64) {
      int b0 = tid * 128;
      for (int i = 0; i < 128; ++i) ++scnt[tid][sids[b0 + i]];
    }
    __syncthreads();
    if (tid == 0) {
      int tot = 0;
      for (int e = 0; e < 8; ++e) {
        off[e] = tot;
        for (int c = 0; c < 64; ++c) { sstart[c][e] = tot; tot += scnt[c][e]; }
      }
      off[8] = tot;
    }
    __syncthreads();
    if (tid < 64) {
      int b0 = tid * 128;
      for (int i = 0; i < 128; ++i) {
        int p = b0 + i;
        int e = sids[p];
        list[sstart[tid][e]++] = p;    // stable within chunk -> deterministic
      }
    }
  }
  // all blocks: grid-stride cvt over a1 then w1
  size_t i = (size_t)blockIdx.x * 256 + tid;
  size_t stride = (size_t)gridDim.x * 256;
  for (; i < N8_A1 + N8_W1; i += stride) {
    if (i < N8_A1) {
      const float4* p = (const float4*)(a1 + i * 8);
      float4 f0 = p[0], f1 = p[1];
      *(s16x8*)(a1b + i * 8) = pack8(f0, f1);
    } else {
      size_t j = i - N8_A1;
      const float4* p = (const float4*)(w1 + j * 8);
      float4 f0 = p[0], f1 = p[1];
      *(s16x8*)(w1b + j * 8) = pack8(f0, f1);
    }
  }
}

// ---------------- GEMM1: act[slot,:] = silu(a1@Wg^T) * (a1@Wu^T) ----------------
// BF=1: bf16 sources + global_load_lds; blocks with mt>=64 instead convert a w2 slice.
// BF=0: fp32 sources, in-loop cvt (fallback when ws too small).
template <int BF>
__global__ __launch_bounds__(256, 2) void gemm1_t(const float* __restrict__ a1,
                                                  const unsigned short* __restrict__ a1b,
                                                  const float* __restrict__ w1,
                                                  const unsigned short* __restrict__ w1b,
                                                  const float* __restrict__ w2f,
                                                  unsigned short* __restrict__ w2b,
                                                  const int* __restrict__ off,
                                                  const int* __restrict__ list,
                                                  unsigned short* __restrict__ act) {
  int e = blockIdx.z, mt = blockIdx.y, nt = blockIdx.x;
  int tid = threadIdx.x;

  if constexpr (BF) {
    // w2 cvt slice rides on extra y-blocks: 44*9*8 = 3168 blocks, 3642 float8-groups each
    if (mt >= 64) {
      const size_t N8_W2 = (size_t)NEXP * KDIM * NINTER / 8;   // 11,534,336
      size_t ci = (size_t)nt + 44u * ((mt - 64) + 9u * e);
      size_t g0 = ci * 3642 + tid;
      size_t end = (ci + 1) * 3642;
      if (end > N8_W2) end = N8_W2;
      for (size_t g = g0; g < end; g += 256) {
        const float4* s = (const float4*)(w2f + g * 8);
        float4 f0 = s[0], f1 = s[1];
        *(s16x8*)(w2b + g * 8) = pack8(f0, f1);
      }
      return;
    }
  }

  int base = off[e];
  int cnt  = off[e + 1] - base;
  if (mt * 128 >= cnt) return;
  __shared__ __align__(16) short lA[128 * 64];
  __shared__ __align__(16) short lBg[128 * 64];
  __shared__ __align__(16) short lBu[128 * 64];
  __shared__ int srow[128];
  if (tid < 128) {
    int r = mt * 128 + tid;
    srow[tid] = (r < cnt) ? (list[base + r] >> 1) : 0;
  }
  __syncthreads();
  int lane = tid & 63, wave = tid >> 6;
  int wm = wave >> 1, wn = wave & 1;
  int lrow = lane & 15, lhi = lane >> 4;
  f32x4 accg[4][4], accu[4][4];
#pragma unroll
  for (int i = 0; i < 4; ++i)
#pragma unroll
    for (int j = 0; j < 4; ++j) { accg[i][j] = (f32x4)(0.f); accu[i][j] = (f32x4)(0.f); }
  int n0 = nt * 128;

  const unsigned short* aSrc[4];
  const unsigned short* gSrc[4];
  const unsigned short* uSrc[4];
  if constexpr (BF) {
    const unsigned short* w1be = w1b + (size_t)e * (2 * NINTER) * KDIM;
    int c = lane & 7;
#pragma unroll
    for (int q = 0; q < 4; ++q) {
      int r = wave * 32 + q * 8 + (lane >> 3);       // LDS row this lane feeds
      int swz = (c ^ (r & 7)) * 8;                   // pre-swizzled source chunk
      aSrc[q] = a1b + (size_t)srow[r] * KDIM + swz;
      gSrc[q] = w1be + (size_t)(n0 + r) * KDIM + swz;
      uSrc[q] = w1be + (size_t)(NINTER + n0 + r) * KDIM + swz;
    }
  }
  const float* w1e = w1 + (size_t)e * (2 * NINTER) * KDIM;

  for (int k0 = 0; k0 < KDIM; k0 += 64) {
    if constexpr (BF) {
#pragma unroll
      for (int q = 0; q < 4; ++q) {
        int row0 = wave * 32 + q * 8;
        __builtin_amdgcn_global_load_lds((const AS1 void*)(aSrc[q] + k0), (AS3 void*)&lA[row0 * 64], 16, 0, 0);
        __builtin_amdgcn_global_load_lds((const AS1 void*)(gSrc[q] + k0), (AS3 void*)&lBg[row0 * 64], 16, 0, 0);
        __builtin_amdgcn_global_load_lds((const AS1 void*)(uSrc[q] + k0), (AS3 void*)&lBu[row0 * 64], 16, 0, 0);
      }
    } else {
#pragma unroll
      for (int c4 = 0; c4 < 4; ++c4) {
        int cid = c4 * 256 + tid;
        int row = cid >> 3, k8 = cid & 7;
        const float* s = a1 + (size_t)srow[row] * KDIM + k0 + k8 * 8;
        float4 f0 = *(const float4*)s;
        float4 f1 = *(const float4*)(s + 4);
        *(s16x8*)&lA[row * 64 + ((k8 ^ (row & 7)) * 8)] = pack8(f0, f1);
      }
#pragma unroll
      for (int c4 = 0; c4 < 4; ++c4) {
        int cid = c4 * 256 + tid;
        int row = cid >> 3, k8 = cid & 7;
        const float* sg = w1e + (size_t)(n0 + row) * KDIM + k0 + k8 * 8;
        const float* su = w1e + (size_t)(NINTER + n0 + row) * KDIM + k0 + k8 * 8;
        float4 g0 = *(const float4*)sg;
        float4 g1 = *(const float4*)(sg + 4);
        float4 u0 = *(const float4*)su;
        float4 u1 = *(const float4*)(su + 4);
        int o = row * 64 + ((k8 ^ (row & 7)) * 8);
        *(s16x8*)&lBg[o] = pack8(g0, g1);
        *(s16x8*)&lBu[o] = pack8(u0, u1);
      }
    }
    __syncthreads();
#pragma unroll
    for (int kk = 0; kk < 2; ++kk) {
      s16x8 af[4], bg[4], bu[4];
      int chunk = kk * 4 + lhi;
#pragma unroll
      for (int i = 0; i < 4; ++i) {
        int r = wm * 64 + i * 16 + lrow;
        af[i] = *(const s16x8*)&lA[r * 64 + ((chunk ^ (r & 7)) * 8)];
      }
#pragma unroll
      for (int j = 0; j < 4; ++j) {
        int r = wn * 64 + j * 16 + lrow;
        int o = r * 64 + ((chunk ^ (r & 7)) * 8);
        bg[j] = *(const s16x8*)&lBg[o];
        bu[j] = *(const s16x8*)&lBu[o];
      }
#pragma unroll
      for (int i = 0; i < 4; ++i)
#pragma unroll
        for (int j = 0; j < 4; ++j) {
          accg[i][j] = __builtin_amdgcn_mfma_f32_16x16x32_bf16(af[i], bg[j], accg[i][j], 0, 0, 0);
          accu[i][j] = __builtin_amdgcn_mfma_f32_16x16x32_bf16(af[i], bu[j], accu[i][j], 0, 0, 0);
        }
    }
    __syncthreads();
  }
#pragma unroll
  for (int i = 0; i < 4; ++i) {
#pragma unroll
    for (int q = 0; q < 4; ++q) {
      int r = wm * 64 + i * 16 + lhi * 4 + q;
      int grow = mt * 128 + r;
      if (grow < cnt) {
        size_t rowoff = (size_t)(base + grow) * NINTER;
#pragma unroll
        for (int j = 0; j < 4; ++j) {
          float g = accg[i][j][q], u = accu[i][j][q];
          float a = (g / (1.f + __expf(-g))) * u;
          int col = n0 + wn * 64 + j * 16 + lrow;
          act[rowoff + col] = (unsigned short)f2bf(a);
        }
      }
    }
  }
}

// ---------------- GEMM2: out[token,:] += tw * (act @ w2[e]^T) ----------------
template <int BF>
__global__ __launch_bounds__(256, 2) void gemm2_t(const unsigned short* __restrict__ act,
                                                  const float* __restrict__ w2,
                                                  const unsigned short* __restrict__ w2b,
                                                  const int* __restrict__ off,
                                                  const int* __restrict__ list,
                                                  const float* __restrict__ tw,
                                                  float* __restrict__ out) {
  int e = blockIdx.z, mt = blockIdx.y, nt = blockIdx.x;
  int base = off[e];
  int cnt  = off[e + 1] - base;
  if (mt * 128 >= cnt) return;
  __shared__ __align__(16) short lA[128 * 64];
  __shared__ __align__(16) short lB[128 * 64];
  int tid = threadIdx.x;
  int lane = tid & 63, wave = tid >> 6;
  int wm = wave >> 1, wn = wave & 1;
  int lrow = lane & 15, lhi = lane >> 4;
  f32x4 acc[4][4];
#pragma unroll
  for (int i = 0; i < 4; ++i)
#pragma unroll
    for (int j = 0; j < 4; ++j) acc[i][j] = (f32x4)(0.f);
  const float* w2e = w2 + (size_t)e * KDIM * NINTER;

  const unsigned short* aSrc[4];
  const unsigned short* bSrc[4];
  if constexpr (BF) {
    const unsigned short* w2be = w2b + (size_t)e * KDIM * NINTER;
    int c = lane & 7;
#pragma unroll
    for (int q = 0; q < 4; ++q) {
      int r = wave * 32 + q * 8 + (lane >> 3);
      int swz = (c ^ (r & 7)) * 8;
      int grow = mt * 128 + r;
      if (grow >= cnt) grow = cnt - 1;
      aSrc[q] = act + (size_t)(base + grow) * NINTER + swz;
      bSrc[q] = w2be + (size_t)(nt * 128 + r) * NINTER + swz;
    }
  }

  for (int k0 = 0; k0 < NINTER; k0 += 64) {
    if constexpr (BF) {
#pragma unroll
      for (int q = 0; q < 4; ++q) {
        int row0 = wave * 32 + q * 8;
        __builtin_amdgcn_global_load_lds((const AS1 void*)(aSrc[q] + k0), (AS3 void*)&lA[row0 * 64], 16, 0, 0);
        __builtin_amdgcn_global_load_lds((const AS1 void*)(bSrc[q] + k0), (AS3 void*)&lB[row0 * 64], 16, 0, 0);
      }
    } else {
#pragma unroll
      for (int c4 = 0; c4 < 4; ++c4) {
        int cid = c4 * 256 + tid;
        int row = cid >> 3, k8 = cid & 7;
        int grow = mt * 128 + row;
        if (grow >= cnt) grow = cnt - 1;
        s16x8 v = *(const s16x8*)(act + (size_t)(base + grow) * NINTER + k0 + k8 * 8);
        *(s16x8*)&lA[row * 64 + ((k8 ^ (row & 7)) * 8)] = v;
      }
#pragma unroll
      for (int c4 = 0; c4 < 4; ++c4) {
        int cid = c4 * 256 + tid;
        int row = cid >> 3, k8 = cid & 7;
        const float* s = w2e + (size_t)(nt * 128 + row) * NINTER + k0 + k8 * 8;
        float4 f0 = *(const float4*)s;
        float4 f1 = *(const float4*)(s + 4);
        *(s16x8*)&lB[row * 64 + ((k8 ^ (row & 7)) * 8)] = pack8(f0, f1);
      }
    }
    __syncthreads();
#pragma unroll
    for (int kk = 0; kk < 2; ++kk) {
      s16x8 af[4], bf[4];
      int chunk = kk * 4 + lhi;
#pragma unroll
      for (int i = 0; i < 4; ++i) {
        int r = wm * 64 + i * 16 + lrow;
        af[i] = *(const s16x8*)&lA[r * 64 + ((chunk ^ (r & 7)) * 8)];
      }
#pragma unroll
      for (int j = 0; j < 4; ++j) {
        int r = wn * 64 + j * 16 + lrow;
        bf[j] = *(const s16x8*)&lB[r * 64 + ((chunk ^ (r & 7)) * 8)];
      }
#pragma unroll
      for (int i = 0; i < 4; ++i)
#pragma unroll
        for (int j = 0; j < 4; ++j)
          acc[i][j] = __builtin_amdgcn_mfma_f32_16x16x32_bf16(af[i], bf[j], acc[i][j], 0, 0, 0);
    }
    __syncthreads();
  }
#pragma unroll
  for (int i = 0; i < 4; ++i) {
#pragma unroll
    for (int q = 0; q < 4; ++q) {
      int r = wm * 64 + i * 16 + lhi * 4 + q;
      int grow = mt * 128 + r;
      if (grow < cnt) {
        int p = list[base + grow];
        int m = p >> 1;
        float wgt = tw[p];
#pragma unroll
        for (int j = 0; j < 4; ++j) {
          int col = nt * 128 + wn * 64 + j * 16 + lrow;
          atomicAdd(&out[(size_t)m * KDIM + col], wgt * acc[i][j][q]);
        }
      }
    }
  }
}

// standalone route kernel for the fallback path
__global__ __launch_bounds__(512) void route_k(const int* __restrict__ ids,
                                               int* __restrict__ off,
                                               int* __restrict__ list) {
  __shared__ int sids[NPAIR];
  __shared__ int scnt[64][8];
  __shared__ int sstart[64][8];
  __shared__ int s_is64;
  int tid = threadIdx.x;
  if (tid == 0) s_is64 = 1;
  __syncthreads();
  for (int i = tid; i < NPAIR / 2; i += 512)
    if (ids[2 * i + 1] != 0) s_is64 = 0;
  __syncthreads();
  int is64 = s_is64;
  for (int i = tid; i < NPAIR; i += 512) {
    int e = is64 ? ids[2 * i] : ids[i];
    if (e < 0) e = 0; if (e > 7) e = 7;
    sids[i] = e;
  }
  if (tid < 64)
    for (int e = 0; e < 8; ++e) scnt[tid][e] = 0;
  __syncthreads();
  if (tid < 64) {
    int b0 = tid * 128;
    for (int i = 0; i < 128; ++i) ++scnt[tid][sids[b0 + i]];
  }
  __syncthreads();
  if (tid == 0) {
    int tot = 0;
    for (int e = 0; e < 8; ++e) {
      off[e] = tot;
      for (int c = 0; c < 64; ++c) { sstart[c][e] = tot; tot += scnt[c][e]; }
    }
    off[8] = tot;
  }
  __syncthreads();
  if (tid < 64) {
    int b0 = tid * 128;
    for (int i = 0; i < 128; ++i) {
      int p = b0 + i;
      int e = sids[p];
      list[sstart[tid][e]++] = p;
    }
  }
}

extern "C" void kernel_launch(void* const* d_in, const int* in_sizes, int n_in,
                              void* d_out, int out_size, void* d_ws, size_t ws_size,
                              hipStream_t stream) {
  const float* a1 = (const float*)d_in[0];
  const float* w1 = (const float*)d_in[1];
  const float* w2 = (const float*)d_in[2];
  const float* tw = (const float*)d_in[3];
  const int*   ids = (const int*)d_in[4];
  float* out = (float*)d_out;

  int* off  = (int*)d_ws;
  int* list = off + 16;
  unsigned short* act = (unsigned short*)((char*)d_ws + 65536);
  size_t actB = (size_t)NPAIR * NINTER * 2;
  unsigned short* a1b = (unsigned short*)((char*)act + actB);
  size_t a1B = (size_t)MTOK * KDIM * 2;
  unsigned short* w1b = (unsigned short*)((char*)a1b + a1B);
  size_t w1B = (size_t)NEXP * 2 * NINTER * KDIM * 2;
  unsigned short* w2b = (unsigned short*)((char*)w1b + w1B);
  size_t w2B = (size_t)NEXP * KDIM * NINTER * 2;
  size_t need = 65536 + actB + a1B + w1B + w2B;

  hipMemsetAsync(d_out, 0, (size_t)MTOK * KDIM * sizeof(float), stream);

  if (ws_size >= need) {
    routecvt_k<<<4096, 256, 0, stream>>>(ids, off, list, a1, a1b, w1, w1b);
    gemm1_t<1><<<dim3(NINTER / 128, 73, NEXP), 256, 0, stream>>>(a1, a1b, w1, w1b, w2, w2b, off, list, act);
    gemm2_t<1><<<dim3(KDIM / 128, 64, NEXP), 256, 0, stream>>>(act, w2, w2b, off, list, tw, out);
  } else {
    route_k<<<1, 512, 0, stream>>>(ids, off, list);
    gemm1_t<0><<<dim3(NINTER / 128, 64, NEXP), 256, 0, stream>>>(a1, a1b, w1, w1b, w2, w2b, off, list, act);
    gemm2_t<0><<<dim3(KDIM / 128, 64, NEXP), 256, 0, stream>>>(act, w2, w2b, off, list, tw, out);
  }
}

// Round 6
// 999.269 us; speedup vs baseline: 1.8259x; 1.0071x over previous
//
#include <hip/hip_runtime.h>
#include <hip/hip_bf16.h>

#define NEXP   8
#define MTOK   4096
#define KDIM   2048
#define NINTER 5632
#define NPAIR  8192   // MTOK * TOPK

#define AS3 __attribute__((address_space(3)))
#define AS1 __attribute__((address_space(1)))

typedef __attribute__((ext_vector_type(4))) float f32x4;
typedef __attribute__((ext_vector_type(8))) short s16x8;

__device__ __forceinline__ short f2bf(float f) {
  union { float f; unsigned u; } v; v.f = f;
  unsigned r = v.u + 0x7FFFu + ((v.u >> 16) & 1u);
  return (short)(r >> 16);
}

__device__ __forceinline__ s16x8 pack8(float4 a, float4 b) {
  s16x8 v;
  v[0] = f2bf(a.x); v[1] = f2bf(a.y); v[2] = f2bf(a.z); v[3] = f2bf(a.w);
  v[4] = f2bf(b.x); v[5] = f2bf(b.y); v[6] = f2bf(b.z); v[7] = f2bf(b.w);
  return v;
}

// ============ fused: routing (block 0) + a1/w1 fp32->bf16 cvt (all blocks) ============
#define N8_A1  ((size_t)MTOK * KDIM / 8)                 // 1,048,576
#define N8_W1  ((size_t)NEXP * 2 * NINTER * KDIM / 8)    // 23,068,672
__global__ __launch_bounds__(256) void routecvt_k(const int* __restrict__ ids,
                                                  int* __restrict__ off,
                                                  int* __restrict__ list,
                                                  const float* __restrict__ a1,
                                                  unsigned short* __restrict__ a1b,
                                                  const float* __restrict__ w1,
                                                  unsigned short* __restrict__ w1b) {
  int tid = threadIdx.x;
  if (blockIdx.x == 0) {
    __shared__ int sids[NPAIR];
    __shared__ int scnt[64][8];
    __shared__ int sstart[64][8];
    __shared__ int s_is64;
    if (tid == 0) s_is64 = 1;
    __syncthreads();
    for (int i = tid; i < NPAIR / 2; i += 256)
      if (ids[2 * i + 1] != 0) s_is64 = 0;   // benign race, only writes 0
    __syncthreads();
    int is64 = s_is64;
    for (int i = tid; i < NPAIR; i += 256) {
      int e = is64 ? ids[2 * i] : ids[i];
      if (e < 0) e = 0; if (e > 7) e = 7;
      sids[i] = e;
    }
    if (tid < 64)
      for (int e = 0; e < 8; ++e) scnt[tid][e] = 0;
    __syncthreads();
    if (tid < 64) {
      int b0 = tid * 128;
      for (int i = 0; i < 128; ++i) ++scnt[tid][sids[b0 + i]];
    }
    __syncthreads();
    if (tid == 0) {
      int tot = 0;
      for (int e = 0; e < 8; ++e) {
        off[e] = tot;
        for (int c = 0; c < 64; ++c) { sstart[c][e] = tot; tot += scnt[c][e]; }
      }
      off[8] = tot;
    }
    __syncthreads();
    if (tid < 64) {
      int b0 = tid * 128;
      for (int i = 0; i < 128; ++i) {
        int p = b0 + i;
        int e = sids[p];
        list[sstart[tid][e]++] = p;    // stable within chunk -> deterministic
      }
    }
  }
  // all blocks: grid-stride cvt over a1 then w1
  size_t i = (size_t)blockIdx.x * 256 + tid;
  size_t stride = (size_t)gridDim.x * 256;
  for (; i < N8_A1 + N8_W1; i += stride) {
    if (i < N8_A1) {
      const float4* p = (const float4*)(a1 + i * 8);
      float4 f0 = p[0], f1 = p[1];
      *(s16x8*)(a1b + i * 8) = pack8(f0, f1);
    } else {
      size_t j = i - N8_A1;
      const float4* p = (const float4*)(w1 + j * 8);
      float4 f0 = p[0], f1 = p[1];
      *(s16x8*)(w1b + j * 8) = pack8(f0, f1);
    }
  }
}

// ---------------- GEMM1: act[slot,:] = silu(a1@Wg^T) * (a1@Wu^T) ----------------
// BF=1: bf16 sources + global_load_lds. Blocks with mt<8 additionally convert a
// 4096-group slice of w2 (fp32->bf16), interleaved into the K-loop stall cycles
// (2816 carriers x 4096 groups = 11,534,336 = whole w2, exactly).
// BF=0: fp32 sources, in-loop cvt (fallback when ws too small).
template <int BF>
__global__ __launch_bounds__(256, 2) void gemm1_t(const float* __restrict__ a1,
                                                  const unsigned short* __restrict__ a1b,
                                                  const float* __restrict__ w1,
                                                  const unsigned short* __restrict__ w1b,
                                                  const float* __restrict__ w2f,
                                                  unsigned short* __restrict__ w2b,
                                                  const int* __restrict__ off,
                                                  const int* __restrict__ list,
                                                  unsigned short* __restrict__ act) {
  int e = blockIdx.z, mt = blockIdx.y, nt = blockIdx.x;
  int tid = threadIdx.x;
  int base = off[e];
  int cnt  = off[e + 1] - base;

  bool carrier = false;
  size_t cb = 0;
  if constexpr (BF) {
    carrier = (mt < 8);
    cb = ((size_t)nt + 44u * ((size_t)mt + 8u * (size_t)e)) * 4096;
  }

  if (mt * 128 >= cnt) {
    if constexpr (BF) {
      if (carrier) {   // rare: expert with <1024 slots; do slice in a tight loop
        for (int s = 0; s < 16; ++s) {
          size_t g = cb + (size_t)s * 256 + tid;
          const float4* p = (const float4*)(w2f + g * 8);
          float4 f0 = p[0], f1 = p[1];
          *(s16x8*)(w2b + g * 8) = pack8(f0, f1);
        }
      }
    }
    return;
  }

  __shared__ __align__(16) short lA[128 * 64];
  __shared__ __align__(16) short lBg[128 * 64];
  __shared__ __align__(16) short lBu[128 * 64];
  __shared__ int srow[128];
  if (tid < 128) {
    int r = mt * 128 + tid;
    srow[tid] = (r < cnt) ? (list[base + r] >> 1) : 0;
  }
  __syncthreads();
  int lane = tid & 63, wave = tid >> 6;
  int wm = wave >> 1, wn = wave & 1;
  int lrow = lane & 15, lhi = lane >> 4;
  f32x4 accg[4][4], accu[4][4];
#pragma unroll
  for (int i = 0; i < 4; ++i)
#pragma unroll
    for (int j = 0; j < 4; ++j) { accg[i][j] = (f32x4)(0.f); accu[i][j] = (f32x4)(0.f); }
  int n0 = nt * 128;

  const unsigned short* aSrc[4];
  const unsigned short* gSrc[4];
  const unsigned short* uSrc[4];
  if constexpr (BF) {
    const unsigned short* w1be = w1b + (size_t)e * (2 * NINTER) * KDIM;
    int c = lane & 7;
#pragma unroll
    for (int q = 0; q < 4; ++q) {
      int r = wave * 32 + q * 8 + (lane >> 3);       // LDS row this lane feeds
      int swz = (c ^ (r & 7)) * 8;                   // pre-swizzled source chunk
      aSrc[q] = a1b + (size_t)srow[r] * KDIM + swz;
      gSrc[q] = w1be + (size_t)(n0 + r) * KDIM + swz;
      uSrc[q] = w1be + (size_t)(NINTER + n0 + r) * KDIM + swz;
    }
  }
  const float* w1e = w1 + (size_t)e * (2 * NINTER) * KDIM;

  for (int k0 = 0; k0 < KDIM; k0 += 64) {
    if constexpr (BF) {
#pragma unroll
      for (int q = 0; q < 4; ++q) {
        int row0 = wave * 32 + q * 8;
        __builtin_amdgcn_global_load_lds((const AS1 void*)(aSrc[q] + k0), (AS3 void*)&lA[row0 * 64], 16, 0, 0);
        __builtin_amdgcn_global_load_lds((const AS1 void*)(gSrc[q] + k0), (AS3 void*)&lBg[row0 * 64], 16, 0, 0);
        __builtin_amdgcn_global_load_lds((const AS1 void*)(uSrc[q] + k0), (AS3 void*)&lBu[row0 * 64], 16, 0, 0);
      }
      // w2 cvt interleave: one 32B->16B group per thread every other K-step;
      // the load drains in the same vmcnt wait as the staging, pack fills stalls.
      int ks = k0 >> 6;
      if (carrier && (ks & 1) == 0) {
        size_t g = cb + (size_t)(ks >> 1) * 256 + tid;
        const float4* p = (const float4*)(w2f + g * 8);
        float4 f0 = p[0], f1 = p[1];
        *(s16x8*)(w2b + g * 8) = pack8(f0, f1);
      }
    } else {
#pragma unroll
      for (int c4 = 0; c4 < 4; ++c4) {
        int cid = c4 * 256 + tid;
        int row = cid >> 3, k8 = cid & 7;
        const float* s = a1 + (size_t)srow[row] * KDIM + k0 + k8 * 8;
        float4 f0 = *(const float4*)s;
        float4 f1 = *(const float4*)(s + 4);
        *(s16x8*)&lA[row * 64 + ((k8 ^ (row & 7)) * 8)] = pack8(f0, f1);
      }
#pragma unroll
      for (int c4 = 0; c4 < 4; ++c4) {
        int cid = c4 * 256 + tid;
        int row = cid >> 3, k8 = cid & 7;
        const float* sg = w1e + (size_t)(n0 + row) * KDIM + k0 + k8 * 8;
        const float* su = w1e + (size_t)(NINTER + n0 + row) * KDIM + k0 + k8 * 8;
        float4 g0 = *(const float4*)sg;
        float4 g1 = *(const float4*)(sg + 4);
        float4 u0 = *(const float4*)su;
        float4 u1 = *(const float4*)(su + 4);
        int o = row * 64 + ((k8 ^ (row & 7)) * 8);
        *(s16x8*)&lBg[o] = pack8(g0, g1);
        *(s16x8*)&lBu[o] = pack8(u0, u1);
      }
    }
    __syncthreads();
#pragma unroll
    for (int kk = 0; kk < 2; ++kk) {
      s16x8 af[4], bg[4], bu[4];
      int chunk = kk * 4 + lhi;
#pragma unroll
      for (int i = 0; i < 4; ++i) {
        int r = wm * 64 + i * 16 + lrow;
        af[i] = *(const s16x8*)&lA[r * 64 + ((chunk ^ (r & 7)) * 8)];
      }
#pragma unroll
      for (int j = 0; j < 4; ++j) {
        int r = wn * 64 + j * 16 + lrow;
        int o = r * 64 + ((chunk ^ (r & 7)) * 8);
        bg[j] = *(const s16x8*)&lBg[o];
        bu[j] = *(const s16x8*)&lBu[o];
      }
#pragma unroll
      for (int i = 0; i < 4; ++i)
#pragma unroll
        for (int j = 0; j < 4; ++j) {
          accg[i][j] = __builtin_amdgcn_mfma_f32_16x16x32_bf16(af[i], bg[j], accg[i][j], 0, 0, 0);
          accu[i][j] = __builtin_amdgcn_mfma_f32_16x16x32_bf16(af[i], bu[j], accu[i][j], 0, 0, 0);
        }
    }
    __syncthreads();
  }
#pragma unroll
  for (int i = 0; i < 4; ++i) {
#pragma unroll
    for (int q = 0; q < 4; ++q) {
      int r = wm * 64 + i * 16 + lhi * 4 + q;
      int grow = mt * 128 + r;
      if (grow < cnt) {
        size_t rowoff = (size_t)(base + grow) * NINTER;
#pragma unroll
        for (int j = 0; j < 4; ++j) {
          float g = accg[i][j][q], u = accu[i][j][q];
          float a = (g / (1.f + __expf(-g))) * u;
          int col = n0 + wn * 64 + j * 16 + lrow;
          act[rowoff + col] = (unsigned short)f2bf(a);
        }
      }
    }
  }
}

// ---------------- GEMM2: out[token,:] += tw * (act @ w2[e]^T) ----------------
template <int BF>
__global__ __launch_bounds__(256, 2) void gemm2_t(const unsigned short* __restrict__ act,
                                                  const float* __restrict__ w2,
                                                  const unsigned short* __restrict__ w2b,
                                                  const int* __restrict__ off,
                                                  const int* __restrict__ list,
                                                  const float* __restrict__ tw,
                                                  float* __restrict__ out) {
  int e = blockIdx.z, mt = blockIdx.y, nt = blockIdx.x;
  int base = off[e];
  int cnt  = off[e + 1] - base;
  if (mt * 128 >= cnt) return;
  __shared__ __align__(16) short lA[128 * 64];
  __shared__ __align__(16) short lB[128 * 64];
  int tid = threadIdx.x;
  int lane = tid & 63, wave = tid >> 6;
  int wm = wave >> 1, wn = wave & 1;
  int lrow = lane & 15, lhi = lane >> 4;
  f32x4 acc[4][4];
#pragma unroll
  for (int i = 0; i < 4; ++i)
#pragma unroll
    for (int j = 0; j < 4; ++j) acc[i][j] = (f32x4)(0.f);
  const float* w2e = w2 + (size_t)e * KDIM * NINTER;

  const unsigned short* aSrc[4];
  const unsigned short* bSrc[4];
  if constexpr (BF) {
    const unsigned short* w2be = w2b + (size_t)e * KDIM * NINTER;
    int c = lane & 7;
#pragma unroll
    for (int q = 0; q < 4; ++q) {
      int r = wave * 32 + q * 8 + (lane >> 3);
      int swz = (c ^ (r & 7)) * 8;
      int grow = mt * 128 + r;
      if (grow >= cnt) grow = cnt - 1;
      aSrc[q] = act + (size_t)(base + grow) * NINTER + swz;
      bSrc[q] = w2be + (size_t)(nt * 128 + r) * NINTER + swz;
    }
  }

  for (int k0 = 0; k0 < NINTER; k0 += 64) {
    if constexpr (BF) {
#pragma unroll
      for (int q = 0; q < 4; ++q) {
        int row0 = wave * 32 + q * 8;
        __builtin_amdgcn_global_load_lds((const AS1 void*)(aSrc[q] + k0), (AS3 void*)&lA[row0 * 64], 16, 0, 0);
        __builtin_amdgcn_global_load_lds((const AS1 void*)(bSrc[q] + k0), (AS3 void*)&lB[row0 * 64], 16, 0, 0);
      }
    } else {
#pragma unroll
      for (int c4 = 0; c4 < 4; ++c4) {
        int cid = c4 * 256 + tid;
        int row = cid >> 3, k8 = cid & 7;
        int grow = mt * 128 + row;
        if (grow >= cnt) grow = cnt - 1;
        s16x8 v = *(const s16x8*)(act + (size_t)(base + grow) * NINTER + k0 + k8 * 8);
        *(s16x8*)&lA[row * 64 + ((k8 ^ (row & 7)) * 8)] = v;
      }
#pragma unroll
      for (int c4 = 0; c4 < 4; ++c4) {
        int cid = c4 * 256 + tid;
        int row = cid >> 3, k8 = cid & 7;
        const float* s = w2e + (size_t)(nt * 128 + row) * NINTER + k0 + k8 * 8;
        float4 f0 = *(const float4*)s;
        float4 f1 = *(const float4*)(s + 4);
        *(s16x8*)&lB[row * 64 + ((k8 ^ (row & 7)) * 8)] = pack8(f0, f1);
      }
    }
    __syncthreads();
#pragma unroll
    for (int kk = 0; kk < 2; ++kk) {
      s16x8 af[4], bf[4];
      int chunk = kk * 4 + lhi;
#pragma unroll
      for (int i = 0; i < 4; ++i) {
        int r = wm * 64 + i * 16 + lrow;
        af[i] = *(const s16x8*)&lA[r * 64 + ((chunk ^ (r & 7)) * 8)];
      }
#pragma unroll
      for (int j = 0; j < 4; ++j) {
        int r = wn * 64 + j * 16 + lrow;
        bf[j] = *(const s16x8*)&lB[r * 64 + ((chunk ^ (r & 7)) * 8)];
      }
#pragma unroll
      for (int i = 0; i < 4; ++i)
#pragma unroll
        for (int j = 0; j < 4; ++j)
          acc[i][j] = __builtin_amdgcn_mfma_f32_16x16x32_bf16(af[i], bf[j], acc[i][j], 0, 0, 0);
    }
    __syncthreads();
  }
#pragma unroll
  for (int i = 0; i < 4; ++i) {
#pragma unroll
    for (int q = 0; q < 4; ++q) {
      int r = wm * 64 + i * 16 + lhi * 4 + q;
      int grow = mt * 128 + r;
      if (grow < cnt) {
        int p = list[base + grow];
        int m = p >> 1;
        float wgt = tw[p];
#pragma unroll
        for (int j = 0; j < 4; ++j) {
          int col = nt * 128 + wn * 64 + j * 16 + lrow;
          atomicAdd(&out[(size_t)m * KDIM + col], wgt * acc[i][j][q]);
        }
      }
    }
  }
}

// standalone route kernel for the fallback path
__global__ __launch_bounds__(512) void route_k(const int* __restrict__ ids,
                                               int* __restrict__ off,
                                               int* __restrict__ list) {
  __shared__ int sids[NPAIR];
  __shared__ int scnt[64][8];
  __shared__ int sstart[64][8];
  __shared__ int s_is64;
  int tid = threadIdx.x;
  if (tid == 0) s_is64 = 1;
  __syncthreads();
  for (int i = tid; i < NPAIR / 2; i += 512)
    if (ids[2 * i + 1] != 0) s_is64 = 0;
  __syncthreads();
  int is64 = s_is64;
  for (int i = tid; i < NPAIR; i += 512) {
    int e = is64 ? ids[2 * i] : ids[i];
    if (e < 0) e = 0; if (e > 7) e = 7;
    sids[i] = e;
  }
  if (tid < 64)
    for (int e = 0; e < 8; ++e) scnt[tid][e] = 0;
  __syncthreads();
  if (tid < 64) {
    int b0 = tid * 128;
    for (int i = 0; i < 128; ++i) ++scnt[tid][sids[b0 + i]];
  }
  __syncthreads();
  if (tid == 0) {
    int tot = 0;
    for (int e = 0; e < 8; ++e) {
      off[e] = tot;
      for (int c = 0; c < 64; ++c) { sstart[c][e] = tot; tot += scnt[c][e]; }
    }
    off[8] = tot;
  }
  __syncthreads();
  if (tid < 64) {
    int b0 = tid * 128;
    for (int i = 0; i < 128; ++i) {
      int p = b0 + i;
      int e = sids[p];
      list[sstart[tid][e]++] = p;
    }
  }
}

extern "C" void kernel_launch(void* const* d_in, const int* in_sizes, int n_in,
                              void* d_out, int out_size, void* d_ws, size_t ws_size,
                              hipStream_t stream) {
  const float* a1 = (const float*)d_in[0];
  const float* w1 = (const float*)d_in[1];
  const float* w2 = (const float*)d_in[2];
  const float* tw = (const float*)d_in[3];
  const int*   ids = (const int*)d_in[4];
  float* out = (float*)d_out;

  int* off  = (int*)d_ws;
  int* list = off + 16;
  unsigned short* act = (unsigned short*)((char*)d_ws + 65536);
  size_t actB = (size_t)NPAIR * NINTER * 2;
  unsigned short* a1b = (unsigned short*)((char*)act + actB);
  size_t a1B = (size_t)MTOK * KDIM * 2;
  unsigned short* w1b = (unsigned short*)((char*)a1b + a1B);
  size_t w1B = (size_t)NEXP * 2 * NINTER * KDIM * 2;
  unsigned short* w2b = (unsigned short*)((char*)w1b + w1B);
  size_t w2B = (size_t)NEXP * KDIM * NINTER * 2;
  size_t need = 65536 + actB + a1B + w1B + w2B;

  hipMemsetAsync(d_out, 0, (size_t)MTOK * KDIM * sizeof(float), stream);

  if (ws_size >= need) {
    routecvt_k<<<4096, 256, 0, stream>>>(ids, off, list, a1, a1b, w1, w1b);
    gemm1_t<1><<<dim3(NINTER / 128, 64, NEXP), 256, 0, stream>>>(a1, a1b, w1, w1b, w2, w2b, off, list, act);
    gemm2_t<1><<<dim3(KDIM / 128, 64, NEXP), 256, 0, stream>>>(act, w2, w2b, off, list, tw, out);
  } else {
    route_k<<<1, 512, 0, stream>>>(ids, off, list);
    gemm1_t<0><<<dim3(NINTER / 128, 64, NEXP), 256, 0, stream>>>(a1, a1b, w1, w1b, w2, w2b, off, list, act);
    gemm2_t<0><<<dim3(KDIM / 128, 64, NEXP), 256, 0, stream>>>(act, w2, w2b, off, list, tw, out);
  }
}